// Round 8
// baseline (825.917 us; speedup 1.0000x reference)
//
#include <hip/hip_runtime.h>

#define T_STEPS 512
#define ROWH 72   // halves per h row (144 B, 16B-aligned): b128 h-reads hit the
                  // 8-cycle wave minimum, zero excess bank conflict (addresses
                  // provably distinct: 9*col+g4 injective for col<16,g4<4)

typedef _Float16 half8 __attribute__((ext_vector_type(8)));
typedef float f32x4 __attribute__((ext_vector_type(4)));

// raw v_rcp_f32 (~1 ulp): plain 1/x without fast-math expands to the IEEE
// div sequence (~10 instrs) — round 6->7 showed this was ~40% of the step.
__device__ __forceinline__ float fastrcp(float v) { return __builtin_amdgcn_rcpf(v); }
__device__ __forceinline__ float sigf(float v) { return fastrcp(1.0f + __expf(-v)); }
__device__ __forceinline__ float tanh_fast(float v) {
    return 1.0f - 2.0f * fastrcp(__expf(2.0f * v) + 1.0f);
}

__device__ __forceinline__ half8 pack8(f32x4 a, f32x4 b) {
    half8 r;
    r[0] = (_Float16)a[0]; r[1] = (_Float16)a[1];
    r[2] = (_Float16)a[2]; r[3] = (_Float16)a[3];
    r[4] = (_Float16)b[0]; r[5] = (_Float16)b[1];
    r[6] = (_Float16)b[2]; r[7] = (_Float16)b[3];
    return r;
}

// MFMA fragment maps (16x16x32):
//   A[16xK32]: row = lane&15, k = (lane>>4)*8 + i
//   B[K32x16]: col = lane&15, k = (lane>>4)*8 + i
//   D[16x16] : col = lane&15, row = (lane>>4)*4 + reg
// 1024-thread WG = TWO independent 16-batch chains (rounds 5-7: padded LDS
// forces 1 WG/CU; with 16 waves/CU that's 4 waves/SIMD -> 128-VGPR grant,
// spill-free at ~90 demand, and 2x the per-SIMD latency-hiding of round 7).
// Per chain: waves 0-3 layer1, waves 4-7 layer2 (one step behind), wave lw
// owns j in [16lw,16lw+16) via col-tiles {lw,lw+4,lw+8,lw+12} -> the 4 gate
// types for (batch,j) sit in one lane's 4 accumulators -> in-register cell
// update. h crosses steps via LDS in fp16 (the MFMA path converts to fp16
// anyway -> no extra rounding on the recurrence; kills 32 cvt + 4 ds_reads
// per L2 wave per step). L1 bias rides the MFMA in the unused k=6 x-slot.
__global__ __launch_bounds__(1024)
void lstm_mfma_kernel(const float* __restrict__ x,
                      const float* __restrict__ W_ih0, const float* __restrict__ W_hh0,
                      const float* __restrict__ b_ih0, const float* __restrict__ b_hh0,
                      const float* __restrict__ W_ih1, const float* __restrict__ W_hh1,
                      const float* __restrict__ b_ih1, const float* __restrict__ b_hh1,
                      const float* __restrict__ W_fc1, const float* __restrict__ b_fc1,
                      const float* __restrict__ W_fc2, const float* __restrict__ b_fc2,
                      float* __restrict__ out)
{
    const int tid   = threadIdx.x;
    const int chain = tid >> 9;          // 0/1: independent batch group
    const int ctid  = tid & 511;
    const int lane  = ctid & 63;         // == tid&63 (chain*512 is wave-aligned)
    const int wid   = ctid >> 6;         // 0..7 within chain
    const int lw    = wid & 3;
    const bool isL2 = wid >= 4;
    const int b0    = blockIdx.x * 32 + chain * 16;
    const int col   = lane & 15;
    const int g4    = lane >> 4;

    // hb[chain][layer][phase][16*ROWH] fp16
    __shared__ __align__(16) _Float16 hb[2][2][2][16 * ROWH];
    __shared__ float fcbuf[32][32];
    __shared__ float padlds[15360];      // occupancy shaping: total ~83.5KB -> 1 WG/CU

    if (blockIdx.x == 0x7fffffff) {      // never true; keeps padlds live
        padlds[tid] = (float)tid;
        out[0] = padlds[0];
    }

    // ---------------- weight fragments (one-time) ----------------
    // L1 chunks: 0 = x (k0..5 = W_ih0, k6 = bias slot), 1..2 = W_hh0 halves
    // L2 chunks: 0..1 = W_ih1 (vs h1), 2..3 = W_hh1 (vs h2)
    half8 wf[4][4];
    float bias[4];
#pragma unroll
    for (int n = 0; n < 4; ++n) {
        const int grow = 16 * (lw + 4 * n) + col;
        if (!isL2) {
            half8 wx;
#pragma unroll
            for (int i = 0; i < 8; ++i) wx[i] = (_Float16)0.f;
            if (g4 == 0) {
                const float2* wp = (const float2*)(W_ih0 + grow * 6);
                float2 w0 = wp[0], w1 = wp[1], w2 = wp[2];
                wx[0] = (_Float16)w0.x; wx[1] = (_Float16)w0.y;
                wx[2] = (_Float16)w1.x; wx[3] = (_Float16)w1.y;
                wx[4] = (_Float16)w2.x; wx[5] = (_Float16)w2.y;
                wx[6] = (_Float16)(b_ih0[grow] + b_hh0[grow]);   // bias slot
            }
            wf[n][0] = wx;
#pragma unroll
            for (int c = 0; c < 2; ++c) {
                const f32x4* wp = (const f32x4*)(W_hh0 + grow * 64 + 32 * c + 8 * g4);
                wf[n][1 + c] = pack8(wp[0], wp[1]);
            }
            wf[n][3] = wf[n][0];   // unused in L1 path
            bias[n] = 0.f;
        } else {
#pragma unroll
            for (int c = 0; c < 2; ++c) {
                const f32x4* wp = (const f32x4*)(W_ih1 + grow * 64 + 32 * c + 8 * g4);
                wf[n][c] = pack8(wp[0], wp[1]);
            }
#pragma unroll
            for (int c = 0; c < 2; ++c) {
                const f32x4* wp = (const f32x4*)(W_hh1 + grow * 64 + 32 * c + 8 * g4);
                wf[n][2 + c] = pack8(wp[0], wp[1]);
            }
            bias[n] = b_ih1[grow] + b_hh1[grow];
        }
    }

    // zero all h buffers
    for (int i = tid; i < 2 * 2 * 2 * 16 * ROWH; i += 1024)
        (&hb[0][0][0][0])[i] = (_Float16)0.f;

    float cst0 = 0.f, cst1 = 0.f, cst2 = 0.f, cst3 = 0.f;
    float xr0=0.f, xr1=0.f, xr2=0.f, xr3=0.f, xr4=0.f, xr5=0.f;
    if (!isL2) {
        const float2* xp = (const float2*)(x + (size_t)(b0 + col) * T_STEPS * 6);
        float2 v0 = xp[0], v1 = xp[1], v2 = xp[2];
        xr0 = v0.x; xr1 = v0.y; xr2 = v1.x; xr3 = v1.y; xr4 = v2.x; xr5 = v2.y;
    }
    __syncthreads();

    int p = 0;
    for (int it = 0; it <= T_STEPS; ++it) {
        if (!isL2) {
            if (it < T_STEPS) {   // layer-1 step t = it
                half8 ax;
#pragma unroll
                for (int i = 0; i < 8; ++i) ax[i] = (_Float16)0.f;
                if (g4 == 0) {
                    ax[0] = (_Float16)xr0; ax[1] = (_Float16)xr1; ax[2] = (_Float16)xr2;
                    ax[3] = (_Float16)xr3; ax[4] = (_Float16)xr4; ax[5] = (_Float16)xr5;
                    ax[6] = (_Float16)1.f;   // bias slot multiplier
                }
                const int tn = (it + 1 < T_STEPS) ? (it + 1) : (T_STEPS - 1);
                const float2* xp = (const float2*)(x + ((size_t)(b0 + col) * T_STEPS + tn) * 6);
                float2 v0 = xp[0], v1 = xp[1], v2 = xp[2];

                const _Float16* hr = &hb[chain][0][p][col * ROWH];
                half8 a0 = *(const half8*)(hr + 8 * g4);
                half8 a1 = *(const half8*)(hr + 32 + 8 * g4);

                f32x4 acc0 = {0.f,0.f,0.f,0.f}, acc1 = {0.f,0.f,0.f,0.f};
                f32x4 acc2 = {0.f,0.f,0.f,0.f}, acc3 = {0.f,0.f,0.f,0.f};
                acc0 = __builtin_amdgcn_mfma_f32_16x16x32_f16(ax, wf[0][0], acc0, 0, 0, 0);
                acc1 = __builtin_amdgcn_mfma_f32_16x16x32_f16(ax, wf[1][0], acc1, 0, 0, 0);
                acc2 = __builtin_amdgcn_mfma_f32_16x16x32_f16(ax, wf[2][0], acc2, 0, 0, 0);
                acc3 = __builtin_amdgcn_mfma_f32_16x16x32_f16(ax, wf[3][0], acc3, 0, 0, 0);
                acc0 = __builtin_amdgcn_mfma_f32_16x16x32_f16(a0, wf[0][1], acc0, 0, 0, 0);
                acc1 = __builtin_amdgcn_mfma_f32_16x16x32_f16(a0, wf[1][1], acc1, 0, 0, 0);
                acc2 = __builtin_amdgcn_mfma_f32_16x16x32_f16(a0, wf[2][1], acc2, 0, 0, 0);
                acc3 = __builtin_amdgcn_mfma_f32_16x16x32_f16(a0, wf[3][1], acc3, 0, 0, 0);
                acc0 = __builtin_amdgcn_mfma_f32_16x16x32_f16(a1, wf[0][2], acc0, 0, 0, 0);
                acc1 = __builtin_amdgcn_mfma_f32_16x16x32_f16(a1, wf[1][2], acc1, 0, 0, 0);
                acc2 = __builtin_amdgcn_mfma_f32_16x16x32_f16(a1, wf[2][2], acc2, 0, 0, 0);
                acc3 = __builtin_amdgcn_mfma_f32_16x16x32_f16(a1, wf[3][2], acc3, 0, 0, 0);

                xr0 = v0.x; xr1 = v0.y; xr2 = v1.x; xr3 = v1.y; xr4 = v2.x; xr5 = v2.y;

                _Float16* hw = &hb[chain][0][1 - p][0];
                const int jc = 16 * lw + col;
#pragma unroll
                for (int r = 0; r < 4; ++r) {
                    float iv = sigf(acc0[r]);
                    float fv = sigf(acc1[r]);
                    float gv = tanh_fast(acc2[r]);
                    float ov = sigf(acc3[r]);
                    float* cp = (r == 0) ? &cst0 : (r == 1) ? &cst1 : (r == 2) ? &cst2 : &cst3;
                    float cn = fv * (*cp) + iv * gv;
                    *cp = cn;
                    hw[(4 * g4 + r) * ROWH + jc] = (_Float16)(ov * tanh_fast(cn));
                }
            }
        } else {
            if (it >= 1) {   // layer-2 step t = it-1
                const _Float16* h1r = &hb[chain][0][p][col * ROWH];
                const _Float16* h2r = &hb[chain][1][p][col * ROWH];
                half8 a0 = *(const half8*)(h1r + 8 * g4);
                half8 a1 = *(const half8*)(h1r + 32 + 8 * g4);
                half8 a2 = *(const half8*)(h2r + 8 * g4);
                half8 a3 = *(const half8*)(h2r + 32 + 8 * g4);

                f32x4 acc0 = {0.f,0.f,0.f,0.f}, acc1 = {0.f,0.f,0.f,0.f};
                f32x4 acc2 = {0.f,0.f,0.f,0.f}, acc3 = {0.f,0.f,0.f,0.f};
                acc0 = __builtin_amdgcn_mfma_f32_16x16x32_f16(a0, wf[0][0], acc0, 0, 0, 0);
                acc1 = __builtin_amdgcn_mfma_f32_16x16x32_f16(a0, wf[1][0], acc1, 0, 0, 0);
                acc2 = __builtin_amdgcn_mfma_f32_16x16x32_f16(a0, wf[2][0], acc2, 0, 0, 0);
                acc3 = __builtin_amdgcn_mfma_f32_16x16x32_f16(a0, wf[3][0], acc3, 0, 0, 0);
                acc0 = __builtin_amdgcn_mfma_f32_16x16x32_f16(a1, wf[0][1], acc0, 0, 0, 0);
                acc1 = __builtin_amdgcn_mfma_f32_16x16x32_f16(a1, wf[1][1], acc1, 0, 0, 0);
                acc2 = __builtin_amdgcn_mfma_f32_16x16x32_f16(a1, wf[2][1], acc2, 0, 0, 0);
                acc3 = __builtin_amdgcn_mfma_f32_16x16x32_f16(a1, wf[3][1], acc3, 0, 0, 0);
                acc0 = __builtin_amdgcn_mfma_f32_16x16x32_f16(a2, wf[0][2], acc0, 0, 0, 0);
                acc1 = __builtin_amdgcn_mfma_f32_16x16x32_f16(a2, wf[1][2], acc1, 0, 0, 0);
                acc2 = __builtin_amdgcn_mfma_f32_16x16x32_f16(a2, wf[2][2], acc2, 0, 0, 0);
                acc3 = __builtin_amdgcn_mfma_f32_16x16x32_f16(a2, wf[3][2], acc3, 0, 0, 0);
                acc0 = __builtin_amdgcn_mfma_f32_16x16x32_f16(a3, wf[0][3], acc0, 0, 0, 0);
                acc1 = __builtin_amdgcn_mfma_f32_16x16x32_f16(a3, wf[1][3], acc1, 0, 0, 0);
                acc2 = __builtin_amdgcn_mfma_f32_16x16x32_f16(a3, wf[2][3], acc2, 0, 0, 0);
                acc3 = __builtin_amdgcn_mfma_f32_16x16x32_f16(a3, wf[3][3], acc3, 0, 0, 0);

                _Float16* hw = &hb[chain][1][1 - p][0];
                const int jc = 16 * lw + col;
#pragma unroll
                for (int r = 0; r < 4; ++r) {
                    float iv = sigf(acc0[r] + bias[0]);
                    float fv = sigf(acc1[r] + bias[1]);
                    float gv = tanh_fast(acc2[r] + bias[2]);
                    float ov = sigf(acc3[r] + bias[3]);
                    float* cp = (r == 0) ? &cst0 : (r == 1) ? &cst1 : (r == 2) ? &cst2 : &cst3;
                    float cn = fv * (*cp) + iv * gv;
                    *cp = cn;
                    hw[(4 * g4 + r) * ROWH + jc] = (_Float16)(ov * tanh_fast(cn));
                }
            }
        }
        __syncthreads();
        p ^= 1;
    }

    // ---- FC head on h2(T-1) (in hb[chain][1][p]) ----
    {
        const int u = tid & 31, bb = tid >> 5;   // 32 batch x 32 units = 1024 thr
        const int ch = bb >> 4, br = bb & 15;
        const _Float16* h2r = &hb[ch][1][p][br * ROWH];
        float s = b_fc1[u];
#pragma unroll 8
        for (int j = 0; j < 64; ++j) s = fmaf(W_fc1[u * 64 + j], (float)h2r[j], s);
        fcbuf[bb][u] = fmaxf(s, 0.f);
    }
    __syncthreads();
    if (tid < 32) {
        float s = b_fc2[0];
#pragma unroll
        for (int k = 0; k < 32; ++k) s = fmaf(W_fc2[k], fcbuf[tid][k], s);
        out[blockIdx.x * 32 + tid] = s;
    }
}

extern "C" void kernel_launch(void* const* d_in, const int* in_sizes, int n_in,
                              void* d_out, int out_size, void* d_ws, size_t ws_size,
                              hipStream_t stream) {
    const float* x     = (const float*)d_in[0];
    const float* W_ih0 = (const float*)d_in[1];
    const float* W_hh0 = (const float*)d_in[2];
    const float* b_ih0 = (const float*)d_in[3];
    const float* b_hh0 = (const float*)d_in[4];
    const float* W_ih1 = (const float*)d_in[5];
    const float* W_hh1 = (const float*)d_in[6];
    const float* b_ih1 = (const float*)d_in[7];
    const float* b_hh1 = (const float*)d_in[8];
    const float* W_fc1 = (const float*)d_in[9];
    const float* b_fc1 = (const float*)d_in[10];
    const float* W_fc2 = (const float*)d_in[11];
    const float* b_fc2 = (const float*)d_in[12];
    float* out = (float*)d_out;

    const int B = in_sizes[0] / (T_STEPS * 6);   // 1024
    lstm_mfma_kernel<<<B / 32, 1024, 0, stream>>>(
        x, W_ih0, W_hh0, b_ih0, b_hh0,
        W_ih1, W_hh1, b_ih1, b_hh1,
        W_fc1, b_fc1, W_fc2, b_fc2, out);
}

// Round 9
// 596.316 us; speedup vs baseline: 1.3850x; 1.3850x over previous
//
#include <hip/hip_runtime.h>

#define TS 512
#define ROWH 72    // fp16 h row stride (144 B): h reads/writes <=2-way bank alias (free)
#define GROW 68    // f32 gate-plane row stride: phase-1 writes 2-way alias (free)

typedef _Float16 half8  __attribute__((ext_vector_type(8)));
typedef _Float16 half2v __attribute__((ext_vector_type(2)));
typedef float    f32x4  __attribute__((ext_vector_type(4)));

// raw v_rcp_f32 (~1 ulp): 1/x without fast-math expands to the ~10-instr IEEE
// div sequence (round 6->7: removing it was -40% wall time).
__device__ __forceinline__ float fastrcp(float v) { return __builtin_amdgcn_rcpf(v); }
__device__ __forceinline__ float sigf(float v) { return fastrcp(1.0f + __expf(-v)); }
__device__ __forceinline__ float tanh_fast(float v) {
    return 1.0f - 2.0f * fastrcp(__expf(2.0f * v) + 1.0f);
}

__device__ __forceinline__ half8 pack8(f32x4 a, f32x4 b) {
    half8 r;
    r[0] = (_Float16)a[0]; r[1] = (_Float16)a[1];
    r[2] = (_Float16)a[2]; r[3] = (_Float16)a[3];
    r[4] = (_Float16)b[0]; r[5] = (_Float16)b[1];
    r[6] = (_Float16)b[2]; r[7] = (_Float16)b[3];
    return r;
}

// MFMA fragment maps (16x16x32):
//   A[16xK32]: row = lane&15 (batch), k = (lane>>4)*8 + i
//   B[K32x16]: col = lane&15 (gate-row), k = (lane>>4)*8 + i
//   D[16x16] : col = lane&15 (gate-row), row = (lane>>4)*4 + reg (batch)
//
// 1024-thr WG = ONE 16-batch chain, 16 waves, 4 waves/SIMD. R8 lesson: 1024-thr
// WGs get a hard ~60-VGPR grant, so per-wave demand must fit ~55: each wave owns
// TWO gate-tiles (16 of the 256 gate rows each) of ONE layer:
//   wave wid<8  : layer1, tiles {T, T+8},  T = wid      (gates {wid>>2, wid>>2+2}, jgrp wid&3)
//   wave wid>=8 : layer2, tiles {T, T+8},  T = wid-8
// L1 wave: 6 MFMAs (x+bias chunk, 2 h-chunks) x 2 tiles, 24 weight VGPRs.
// L2 wave: 8 MFMAs (2 W_ih1 + 2 W_hh1 chunks) x 2 tiles, 32 weight VGPRs.
// Cell update moved to a separate phase: phase1 writes activated gate planes to
// gbuf; phase2 has all 1024 threads update 2 (batch,j) cells each (c in regs),
// writing fp16 h. 2 barriers/step. L2 runs one step behind L1 (double-buffered h).
__global__ __launch_bounds__(1024)
void lstm_mfma_kernel(const float* __restrict__ x,
                      const float* __restrict__ W_ih0, const float* __restrict__ W_hh0,
                      const float* __restrict__ b_ih0, const float* __restrict__ b_hh0,
                      const float* __restrict__ W_ih1, const float* __restrict__ W_hh1,
                      const float* __restrict__ b_ih1, const float* __restrict__ b_hh1,
                      const float* __restrict__ W_fc1, const float* __restrict__ b_fc1,
                      const float* __restrict__ W_fc2, const float* __restrict__ b_fc2,
                      float* __restrict__ out)
{
    const int tid  = threadIdx.x;
    const int lane = tid & 63;
    const int wid  = tid >> 6;          // 0..15
    const int role = wid >> 3;          // 0 = layer1, 1 = layer2
    const int w    = wid & 7;
    const int gA   = w >> 2;            // tile-A gate (0/1); tile-B gate = gA+2
    const int jg   = w & 3;             // j-group (16 cols)
    const int col  = lane & 15;
    const int g4   = lane >> 4;
    const int b0   = blockIdx.x * 16;

    __shared__ __align__(16) _Float16 hb[2][2][16 * ROWH];   // [layer][phase][batch*ROWH]
    __shared__ __align__(16) float gbuf[2][4][16][GROW];     // [layer][gate][batch][j]
    __shared__ float fcbuf[16][32];

    // ---------------- weight fragments (one-time) ----------------
    const int growA = 64 * gA + 16 * jg + col;        // gate row of tile A
    const int growB = growA + 128;                    // tile B (gate gA+2)
    half8 wf0, wf1, wf2, wf3, wf4, wf5, wf6, wf7;
    float biasA = 0.f, biasB = 0.f;
    if (role == 0) {
        // wf0/wf1 = x+bias chunk (tileA/B); wf2,wf3 = W_hh0 tileA halves; wf4,wf5 = tileB
        half8 wxA, wxB;
#pragma unroll
        for (int i = 0; i < 8; ++i) { wxA[i] = (_Float16)0.f; wxB[i] = (_Float16)0.f; }
        if (g4 == 0) {
            const float2* pa = (const float2*)(W_ih0 + growA * 6);
            float2 a0 = pa[0], a1 = pa[1], a2 = pa[2];
            wxA[0]=(_Float16)a0.x; wxA[1]=(_Float16)a0.y; wxA[2]=(_Float16)a1.x;
            wxA[3]=(_Float16)a1.y; wxA[4]=(_Float16)a2.x; wxA[5]=(_Float16)a2.y;
            wxA[6]=(_Float16)(b_ih0[growA] + b_hh0[growA]);
            const float2* pb = (const float2*)(W_ih0 + growB * 6);
            float2 c0 = pb[0], c1 = pb[1], c2 = pb[2];
            wxB[0]=(_Float16)c0.x; wxB[1]=(_Float16)c0.y; wxB[2]=(_Float16)c1.x;
            wxB[3]=(_Float16)c1.y; wxB[4]=(_Float16)c2.x; wxB[5]=(_Float16)c2.y;
            wxB[6]=(_Float16)(b_ih0[growB] + b_hh0[growB]);
        }
        wf0 = wxA; wf1 = wxB;
        {
            const f32x4* p = (const f32x4*)(W_hh0 + growA * 64 + 8 * g4);
            wf2 = pack8(p[0], p[1]);
            const f32x4* q = (const f32x4*)(W_hh0 + growA * 64 + 32 + 8 * g4);
            wf3 = pack8(q[0], q[1]);
            const f32x4* r = (const f32x4*)(W_hh0 + growB * 64 + 8 * g4);
            wf4 = pack8(r[0], r[1]);
            const f32x4* s = (const f32x4*)(W_hh0 + growB * 64 + 32 + 8 * g4);
            wf5 = pack8(s[0], s[1]);
        }
        wf6 = wf0; wf7 = wf1;   // unused on L1 path
    } else {
        // wf0,1 = W_ih1 tileA halves; wf2,3 = W_hh1 tileA; wf4,5 = W_ih1 tileB; wf6,7 = W_hh1 tileB
        const f32x4* p;
        p = (const f32x4*)(W_ih1 + growA * 64 +      8 * g4); wf0 = pack8(p[0], p[1]);
        p = (const f32x4*)(W_ih1 + growA * 64 + 32 + 8 * g4); wf1 = pack8(p[0], p[1]);
        p = (const f32x4*)(W_hh1 + growA * 64 +      8 * g4); wf2 = pack8(p[0], p[1]);
        p = (const f32x4*)(W_hh1 + growA * 64 + 32 + 8 * g4); wf3 = pack8(p[0], p[1]);
        p = (const f32x4*)(W_ih1 + growB * 64 +      8 * g4); wf4 = pack8(p[0], p[1]);
        p = (const f32x4*)(W_ih1 + growB * 64 + 32 + 8 * g4); wf5 = pack8(p[0], p[1]);
        p = (const f32x4*)(W_hh1 + growB * 64 +      8 * g4); wf6 = pack8(p[0], p[1]);
        p = (const f32x4*)(W_hh1 + growB * 64 + 32 + 8 * g4); wf7 = pack8(p[0], p[1]);
        biasA = b_ih1[growA] + b_hh1[growA];
        biasB = b_ih1[growB] + b_hh1[growB];
    }

    // zero h buffers
    for (int i = tid; i < 2 * 2 * 16 * ROWH; i += 1024)
        (&hb[0][0][0])[i] = (_Float16)0.f;

    // phase-2 update mapping: thread -> (layer L, batch b, j = 2*j2, 2*j2+1)
    const int uL  = tid >> 9;
    const int ub  = (tid >> 5) & 15;
    const int uj2 = tid & 31;
    float c0 = 0.f, c1 = 0.f;           // cell state for the 2 owned (b,j) cells

    // x(t=0) prefetch (L1 waves; lane's batch = col, dup across g4 -> L1-cached)
    float xr0=0.f, xr1=0.f, xr2=0.f, xr3=0.f, xr4=0.f, xr5=0.f;
    if (role == 0) {
        const float2* xp = (const float2*)(x + (size_t)(b0 + col) * TS * 6);
        float2 v0 = xp[0], v1 = xp[1], v2 = xp[2];
        xr0=v0.x; xr1=v0.y; xr2=v1.x; xr3=v1.y; xr4=v2.x; xr5=v2.y;
    }
    __syncthreads();

    int p = 0;
    for (int it = 0; it <= TS; ++it) {
        // ---------------- phase 1: gate MFMAs + activation -> gbuf ----------------
        if (role == 0) {
            if (it < TS) {
                half8 ax;
#pragma unroll
                for (int i = 0; i < 8; ++i) ax[i] = (_Float16)0.f;
                if (g4 == 0) {
                    ax[0]=(_Float16)xr0; ax[1]=(_Float16)xr1; ax[2]=(_Float16)xr2;
                    ax[3]=(_Float16)xr3; ax[4]=(_Float16)xr4; ax[5]=(_Float16)xr5;
                    ax[6]=(_Float16)1.f;   // bias multiplier
                }
                const int tn = (it + 1 < TS) ? (it + 1) : (TS - 1);
                const float2* xp = (const float2*)(x + ((size_t)(b0 + col) * TS + tn) * 6);
                float2 v0 = xp[0], v1 = xp[1], v2 = xp[2];

                const _Float16* hr = &hb[0][p][col * ROWH];
                half8 a0 = *(const half8*)(hr + 8 * g4);
                half8 a1 = *(const half8*)(hr + 32 + 8 * g4);

                f32x4 accA = {0.f,0.f,0.f,0.f}, accB = {0.f,0.f,0.f,0.f};
                accA = __builtin_amdgcn_mfma_f32_16x16x32_f16(ax, wf0, accA, 0, 0, 0);
                accB = __builtin_amdgcn_mfma_f32_16x16x32_f16(ax, wf1, accB, 0, 0, 0);
                accA = __builtin_amdgcn_mfma_f32_16x16x32_f16(a0, wf2, accA, 0, 0, 0);
                accB = __builtin_amdgcn_mfma_f32_16x16x32_f16(a0, wf4, accB, 0, 0, 0);
                accA = __builtin_amdgcn_mfma_f32_16x16x32_f16(a1, wf3, accA, 0, 0, 0);
                accB = __builtin_amdgcn_mfma_f32_16x16x32_f16(a1, wf5, accB, 0, 0, 0);

                xr0=v0.x; xr1=v0.y; xr2=v1.x; xr3=v1.y; xr4=v2.x; xr5=v2.y;

                const int jc = 16 * jg + col;
#pragma unroll
                for (int r = 0; r < 4; ++r) {
                    float aA = sigf(accA[r]);                                  // gates 0/1: sigmoid
                    float aB = (gA == 0) ? tanh_fast(accB[r]) : sigf(accB[r]); // gate 2: tanh, 3: sig
                    gbuf[0][gA    ][4 * g4 + r][jc] = aA;
                    gbuf[0][gA + 2][4 * g4 + r][jc] = aB;
                }
            }
        } else {
            if (it >= 1) {
                const _Float16* h1r = &hb[0][p][col * ROWH];
                const _Float16* h2r = &hb[1][p][col * ROWH];
                half8 a0 = *(const half8*)(h1r + 8 * g4);
                half8 a1 = *(const half8*)(h1r + 32 + 8 * g4);

                f32x4 accA = {0.f,0.f,0.f,0.f}, accB = {0.f,0.f,0.f,0.f};
                accA = __builtin_amdgcn_mfma_f32_16x16x32_f16(a0, wf0, accA, 0, 0, 0);
                accB = __builtin_amdgcn_mfma_f32_16x16x32_f16(a0, wf4, accB, 0, 0, 0);
                accA = __builtin_amdgcn_mfma_f32_16x16x32_f16(a1, wf1, accA, 0, 0, 0);
                accB = __builtin_amdgcn_mfma_f32_16x16x32_f16(a1, wf5, accB, 0, 0, 0);

                half8 a2 = *(const half8*)(h2r + 8 * g4);
                half8 a3 = *(const half8*)(h2r + 32 + 8 * g4);
                accA = __builtin_amdgcn_mfma_f32_16x16x32_f16(a2, wf2, accA, 0, 0, 0);
                accB = __builtin_amdgcn_mfma_f32_16x16x32_f16(a2, wf6, accB, 0, 0, 0);
                accA = __builtin_amdgcn_mfma_f32_16x16x32_f16(a3, wf3, accA, 0, 0, 0);
                accB = __builtin_amdgcn_mfma_f32_16x16x32_f16(a3, wf7, accB, 0, 0, 0);

                const int jc = 16 * jg + col;
#pragma unroll
                for (int r = 0; r < 4; ++r) {
                    float aA = sigf(accA[r] + biasA);
                    float aB = (gA == 0) ? tanh_fast(accB[r] + biasB) : sigf(accB[r] + biasB);
                    gbuf[1][gA    ][4 * g4 + r][jc] = aA;
                    gbuf[1][gA + 2][4 * g4 + r][jc] = aB;
                }
            }
        }
        __syncthreads();   // gates ready

        // ---------------- phase 2: cell/hidden update (all 1024 threads) ----------------
        {
            const bool valid = (uL == 0) ? (it < TS) : (it >= 1);
            if (valid) {
                const float2 gi = *(const float2*)&gbuf[uL][0][ub][2 * uj2];
                const float2 gf = *(const float2*)&gbuf[uL][1][ub][2 * uj2];
                const float2 gg = *(const float2*)&gbuf[uL][2][ub][2 * uj2];
                const float2 go = *(const float2*)&gbuf[uL][3][ub][2 * uj2];
                c0 = gf.x * c0 + gi.x * gg.x;
                c1 = gf.y * c1 + gi.y * gg.y;
                half2v hv;
                hv[0] = (_Float16)(go.x * tanh_fast(c0));
                hv[1] = (_Float16)(go.y * tanh_fast(c1));
                *(half2v*)&hb[uL][1 - p][ub * ROWH + 2 * uj2] = hv;
            }
        }
        __syncthreads();   // h ready
        p ^= 1;
    }

    // ---------------- FC head on h2(TS-1) (in hb[1][p]) ----------------
    if (tid < 512) {
        const int u = tid & 31, bb = tid >> 5;   // 16 batch x 32 units
        const _Float16* h2r = &hb[1][p][bb * ROWH];
        float s = b_fc1[u];
#pragma unroll 8
        for (int j = 0; j < 64; ++j) s = fmaf(W_fc1[u * 64 + j], (float)h2r[j], s);
        fcbuf[bb][u] = fmaxf(s, 0.f);
    }
    __syncthreads();
    if (tid < 16) {
        float s = b_fc2[0];
#pragma unroll
        for (int k = 0; k < 32; ++k) s = fmaf(W_fc2[k], fcbuf[tid][k], s);
        out[b0 + tid] = s;
    }
}

extern "C" void kernel_launch(void* const* d_in, const int* in_sizes, int n_in,
                              void* d_out, int out_size, void* d_ws, size_t ws_size,
                              hipStream_t stream) {
    const float* x     = (const float*)d_in[0];
    const float* W_ih0 = (const float*)d_in[1];
    const float* W_hh0 = (const float*)d_in[2];
    const float* b_ih0 = (const float*)d_in[3];
    const float* b_hh0 = (const float*)d_in[4];
    const float* W_ih1 = (const float*)d_in[5];
    const float* W_hh1 = (const float*)d_in[6];
    const float* b_ih1 = (const float*)d_in[7];
    const float* b_hh1 = (const float*)d_in[8];
    const float* W_fc1 = (const float*)d_in[9];
    const float* b_fc1 = (const float*)d_in[10];
    const float* W_fc2 = (const float*)d_in[11];
    const float* b_fc2 = (const float*)d_in[12];
    float* out = (float*)d_out;

    const int B = in_sizes[0] / (TS * 6);   // 1024
    lstm_mfma_kernel<<<B / 16, 1024, 0, stream>>>(
        x, W_ih0, W_hh0, b_ih0, b_hh0,
        W_ih1, W_hh1, b_ih1, b_hh1,
        W_fc1, b_fc1, W_fc2, b_fc2, out);
}

// Round 11
// 448.998 us; speedup vs baseline: 1.8395x; 1.3281x over previous
//
#include <hip/hip_runtime.h>

#define TS 512
#define HR 72     // fp16 h row stride (144 B)
#define GROW 68   // f32 gate-plane row stride

typedef _Float16 half8 __attribute__((ext_vector_type(8)));
typedef float    f32x4 __attribute__((ext_vector_type(4)));

// raw v_rcp_f32 (~1 ulp): 1/x without fast-math expands to the ~10-instr IEEE
// div sequence (round 6->7: removing it was -40% wall time).
__device__ __forceinline__ float fastrcp(float v) { return __builtin_amdgcn_rcpf(v); }
__device__ __forceinline__ float sigf(float v) { return fastrcp(1.0f + __expf(-v)); }
__device__ __forceinline__ float tanh_fast(float v) {
    return 1.0f - 2.0f * fastrcp(__expf(2.0f * v) + 1.0f);
}

__device__ __forceinline__ half8 pack8(f32x4 a, f32x4 b) {
    half8 r;
    r[0] = (_Float16)a[0]; r[1] = (_Float16)a[1];
    r[2] = (_Float16)a[2]; r[3] = (_Float16)a[3];
    r[4] = (_Float16)b[0]; r[5] = (_Float16)b[1];
    r[6] = (_Float16)b[2]; r[7] = (_Float16)b[3];
    return r;
}

// R9 lesson: the step is ISSUE-bound per SIMD, and only 64/256 CUs were used.
// This round: 4 batches/WG -> grid 256 WGs (full chip). Per-CU activation /
// update / LDS issue load drops 4x. MFMA tiles keep M=16 with 4 real rows
// (matrix pipe is 4.5% utilized - waste is free).
//
// 1024 thr = 16 waves, 4 waves/SIMD (LDS padded ~84KB -> 1 WG/CU; 1024-thr WGs
// get a ~60-VGPR grant (R8/R9), per-wave demand <=~55 here).
// Wave wid<8: layer1; wid>=8: layer2 (one step behind). Within role: gA=w>>2,
// jg=w&3; tiles = gates {gA, gA+2}, j in [16jg,16jg+16).
// Phase 1: MFMA only, RAW gate sums -> gbuf (writes masked to g4==0: batches
// live in D rows 0-3). L1 bias rides the MFMA k=6 x-slot.
// Phase 2: 512 threads, 1 cell each: thread (L=tid>>8, b=(tid>>6)&3, j=tid&63)
// applies all 4 activations + cell update + fp16 h write (L2 bias in regs).
__global__ __launch_bounds__(1024)
void lstm_mfma_kernel(const float* __restrict__ x,
                      const float* __restrict__ W_ih0, const float* __restrict__ W_hh0,
                      const float* __restrict__ b_ih0, const float* __restrict__ b_hh0,
                      const float* __restrict__ W_ih1, const float* __restrict__ W_hh1,
                      const float* __restrict__ b_ih1, const float* __restrict__ b_hh1,
                      const float* __restrict__ W_fc1, const float* __restrict__ b_fc1,
                      const float* __restrict__ W_fc2, const float* __restrict__ b_fc2,
                      float* __restrict__ out)
{
    const int tid  = threadIdx.x;
    const int lane = tid & 63;
    const int wid  = tid >> 6;          // 0..15
    const int role = wid >> 3;          // 0 = layer1, 1 = layer2
    const int w    = wid & 7;
    const int gA   = w >> 2;            // tile-A gate (0/1); tile-B gate = gA+2
    const int jg   = w & 3;             // j-group
    const int col  = lane & 15;
    const int g4   = lane >> 4;
    const int b0   = blockIdx.x * 4;

    __shared__ __align__(16) _Float16 hb[2][2][4 * HR];   // [layer][phase][batch*HR]
    __shared__ __align__(16) float gbuf[2][4][4][GROW];   // [layer][gate][batch][j] RAW
    __shared__ float fcbuf[4][32];
    __shared__ float padlds[18432];     // pad -> ~84KB: 1 WG/CU (grant ~60, R8-proven)

    if (blockIdx.x == 0x7fffffff) {     // never true; keeps padlds live
        padlds[tid] = (float)tid;
        out[0] = padlds[0];
    }

    // ---------------- weight fragments (one-time) ----------------
    const int growA = 64 * gA + 16 * jg + col;   // gate row of tile A
    const int growB = growA + 128;               // tile B (gate gA+2)
    half8 wf0, wf1, wf2, wf3, wf4, wf5, wf6, wf7;
    if (role == 0) {
        half8 wxA, wxB;
#pragma unroll
        for (int i = 0; i < 8; ++i) { wxA[i] = (_Float16)0.f; wxB[i] = (_Float16)0.f; }
        if (g4 == 0) {
            const float2* pa = (const float2*)(W_ih0 + growA * 6);
            float2 a0 = pa[0], a1 = pa[1], a2 = pa[2];
            wxA[0]=(_Float16)a0.x; wxA[1]=(_Float16)a0.y; wxA[2]=(_Float16)a1.x;
            wxA[3]=(_Float16)a1.y; wxA[4]=(_Float16)a2.x; wxA[5]=(_Float16)a2.y;
            wxA[6]=(_Float16)(b_ih0[growA] + b_hh0[growA]);
            const float2* pb = (const float2*)(W_ih0 + growB * 6);
            float2 c0 = pb[0], c1 = pb[1], c2 = pb[2];
            wxB[0]=(_Float16)c0.x; wxB[1]=(_Float16)c0.y; wxB[2]=(_Float16)c1.x;
            wxB[3]=(_Float16)c1.y; wxB[4]=(_Float16)c2.x; wxB[5]=(_Float16)c2.y;
            wxB[6]=(_Float16)(b_ih0[growB] + b_hh0[growB]);
        }
        wf0 = wxA; wf1 = wxB;
        const f32x4* p;
        p = (const f32x4*)(W_hh0 + growA * 64 +      8 * g4); wf2 = pack8(p[0], p[1]);
        p = (const f32x4*)(W_hh0 + growA * 64 + 32 + 8 * g4); wf3 = pack8(p[0], p[1]);
        p = (const f32x4*)(W_hh0 + growB * 64 +      8 * g4); wf4 = pack8(p[0], p[1]);
        p = (const f32x4*)(W_hh0 + growB * 64 + 32 + 8 * g4); wf5 = pack8(p[0], p[1]);
        wf6 = wf0; wf7 = wf1;   // unused on L1 path
    } else {
        const f32x4* p;
        p = (const f32x4*)(W_ih1 + growA * 64 +      8 * g4); wf0 = pack8(p[0], p[1]);
        p = (const f32x4*)(W_ih1 + growA * 64 + 32 + 8 * g4); wf1 = pack8(p[0], p[1]);
        p = (const f32x4*)(W_hh1 + growA * 64 +      8 * g4); wf2 = pack8(p[0], p[1]);
        p = (const f32x4*)(W_hh1 + growA * 64 + 32 + 8 * g4); wf3 = pack8(p[0], p[1]);
        p = (const f32x4*)(W_ih1 + growB * 64 +      8 * g4); wf4 = pack8(p[0], p[1]);
        p = (const f32x4*)(W_ih1 + growB * 64 + 32 + 8 * g4); wf5 = pack8(p[0], p[1]);
        p = (const f32x4*)(W_hh1 + growB * 64 +      8 * g4); wf6 = pack8(p[0], p[1]);
        p = (const f32x4*)(W_hh1 + growB * 64 + 32 + 8 * g4); wf7 = pack8(p[0], p[1]);
    }

    // phase-2 ownership: thread (L, b, j), one cell each (tid < 512)
    const int uL = tid >> 8;
    const int ub = (tid >> 6) & 3;
    const int uj = tid & 63;
    float bi = 0.f, bf = 0.f, bg = 0.f, bo = 0.f;   // L2 bias (L1 bias is in MFMA)
    if (tid < 512 && uL == 1) {
        bi = b_ih1[uj]       + b_hh1[uj];
        bf = b_ih1[64 + uj]  + b_hh1[64 + uj];
        bg = b_ih1[128 + uj] + b_hh1[128 + uj];
        bo = b_ih1[192 + uj] + b_hh1[192 + uj];
    }
    float c = 0.f;

    // zero h buffers
    for (int i = tid; i < 2 * 2 * 4 * HR; i += 1024)
        (&hb[0][0][0])[i] = (_Float16)0.f;

    // x(t=0) prefetch (L1 waves; batch = col&3 — dup across lanes, L1-cached)
    float xr0=0.f, xr1=0.f, xr2=0.f, xr3=0.f, xr4=0.f, xr5=0.f;
    if (role == 0) {
        const float2* xp = (const float2*)(x + (size_t)(b0 + (col & 3)) * TS * 6);
        float2 v0 = xp[0], v1 = xp[1], v2 = xp[2];
        xr0=v0.x; xr1=v0.y; xr2=v1.x; xr3=v1.y; xr4=v2.x; xr5=v2.y;
    }
    __syncthreads();

    int p = 0;
    for (int it = 0; it <= TS; ++it) {
        // ---------------- phase 1: raw gate MFMAs -> gbuf ----------------
        if (role == 0) {
            if (it < TS) {
                half8 ax;
#pragma unroll
                for (int i = 0; i < 8; ++i) ax[i] = (_Float16)0.f;
                if (g4 == 0) {
                    ax[0]=(_Float16)xr0; ax[1]=(_Float16)xr1; ax[2]=(_Float16)xr2;
                    ax[3]=(_Float16)xr3; ax[4]=(_Float16)xr4; ax[5]=(_Float16)xr5;
                    ax[6]=(_Float16)1.f;   // bias multiplier
                }
                const int tn = (it + 1 < TS) ? (it + 1) : (TS - 1);
                const float2* xp = (const float2*)(x + ((size_t)(b0 + (col & 3)) * TS + tn) * 6);
                float2 v0 = xp[0], v1 = xp[1], v2 = xp[2];

                const _Float16* hr = &hb[0][p][(col & 3) * HR];
                half8 a0 = *(const half8*)(hr + 8 * g4);
                half8 a1 = *(const half8*)(hr + 32 + 8 * g4);

                f32x4 accA = {0.f,0.f,0.f,0.f}, accB = {0.f,0.f,0.f,0.f};
                accA = __builtin_amdgcn_mfma_f32_16x16x32_f16(ax, wf0, accA, 0, 0, 0);
                accB = __builtin_amdgcn_mfma_f32_16x16x32_f16(ax, wf1, accB, 0, 0, 0);
                accA = __builtin_amdgcn_mfma_f32_16x16x32_f16(a0, wf2, accA, 0, 0, 0);
                accB = __builtin_amdgcn_mfma_f32_16x16x32_f16(a0, wf4, accB, 0, 0, 0);
                accA = __builtin_amdgcn_mfma_f32_16x16x32_f16(a1, wf3, accA, 0, 0, 0);
                accB = __builtin_amdgcn_mfma_f32_16x16x32_f16(a1, wf5, accB, 0, 0, 0);

                xr0=v0.x; xr1=v0.y; xr2=v1.x; xr3=v1.y; xr4=v2.x; xr5=v2.y;

                if (g4 == 0) {
                    const int jc = 16 * jg + col;
#pragma unroll
                    for (int r = 0; r < 4; ++r) {
                        gbuf[0][gA    ][r][jc] = accA[r];
                        gbuf[0][gA + 2][r][jc] = accB[r];
                    }
                }
            }
        } else {
            if (it >= 1) {
                const _Float16* h1r = &hb[0][p][(col & 3) * HR];
                const _Float16* h2r = &hb[1][p][(col & 3) * HR];
                half8 a0 = *(const half8*)(h1r + 8 * g4);
                half8 a1 = *(const half8*)(h1r + 32 + 8 * g4);
                half8 a2 = *(const half8*)(h2r + 8 * g4);
                half8 a3 = *(const half8*)(h2r + 32 + 8 * g4);

                f32x4 accA = {0.f,0.f,0.f,0.f}, accB = {0.f,0.f,0.f,0.f};
                accA = __builtin_amdgcn_mfma_f32_16x16x32_f16(a0, wf0, accA, 0, 0, 0);
                accB = __builtin_amdgcn_mfma_f32_16x16x32_f16(a0, wf4, accB, 0, 0, 0);
                accA = __builtin_amdgcn_mfma_f32_16x16x32_f16(a1, wf1, accA, 0, 0, 0);
                accB = __builtin_amdgcn_mfma_f32_16x16x32_f16(a1, wf5, accB, 0, 0, 0);
                accA = __builtin_amdgcn_mfma_f32_16x16x32_f16(a2, wf2, accA, 0, 0, 0);
                accB = __builtin_amdgcn_mfma_f32_16x16x32_f16(a2, wf6, accB, 0, 0, 0);
                accA = __builtin_amdgcn_mfma_f32_16x16x32_f16(a3, wf3, accA, 0, 0, 0);
                accB = __builtin_amdgcn_mfma_f32_16x16x32_f16(a3, wf7, accB, 0, 0, 0);

                if (g4 == 0) {
                    const int jc = 16 * jg + col;
#pragma unroll
                    for (int r = 0; r < 4; ++r) {
                        gbuf[1][gA    ][r][jc] = accA[r];
                        gbuf[1][gA + 2][r][jc] = accB[r];
                    }
                }
            }
        }
        __syncthreads();   // raw gates ready

        // ------- phase 2: activations + cell/hidden update (512 threads) -------
        if (tid < 512) {
            const bool valid = (uL == 0) ? (it < TS) : (it >= 1);
            if (valid) {
                const float gi = gbuf[uL][0][ub][uj] + bi;
                const float gf = gbuf[uL][1][ub][uj] + bf;
                const float gg = gbuf[uL][2][ub][uj] + bg;
                const float go = gbuf[uL][3][ub][uj] + bo;
                const float iv = sigf(gi);
                const float fv = sigf(gf);
                const float gv = tanh_fast(gg);
                const float ov = sigf(go);
                c = fv * c + iv * gv;
                hb[uL][1 - p][ub * HR + uj] = (_Float16)(ov * tanh_fast(c));
            }
        }
        __syncthreads();   // h ready
        p ^= 1;
    }

    // ---------------- FC head on h2(TS-1) (in hb[1][p]) ----------------
    if (tid < 128) {
        const int u = tid & 31, bb = tid >> 5;   // 4 batch x 32 units
        const _Float16* h2r = &hb[1][p][bb * HR];
        float s = b_fc1[u];
#pragma unroll 8
        for (int j = 0; j < 64; ++j) s = fmaf(W_fc1[u * 64 + j], (float)h2r[j], s);
        fcbuf[bb][u] = fmaxf(s, 0.f);
    }
    __syncthreads();
    if (tid < 4) {
        float s = b_fc2[0];
#pragma unroll
        for (int k = 0; k < 32; ++k) s = fmaf(W_fc2[k], fcbuf[tid][k], s);
        out[b0 + tid] = s;
    }
}

extern "C" void kernel_launch(void* const* d_in, const int* in_sizes, int n_in,
                              void* d_out, int out_size, void* d_ws, size_t ws_size,
                              hipStream_t stream) {
    const float* x     = (const float*)d_in[0];
    const float* W_ih0 = (const float*)d_in[1];
    const float* W_hh0 = (const float*)d_in[2];
    const float* b_ih0 = (const float*)d_in[3];
    const float* b_hh0 = (const float*)d_in[4];
    const float* W_ih1 = (const float*)d_in[5];
    const float* W_hh1 = (const float*)d_in[6];
    const float* b_ih1 = (const float*)d_in[7];
    const float* b_hh1 = (const float*)d_in[8];
    const float* W_fc1 = (const float*)d_in[9];
    const float* b_fc1 = (const float*)d_in[10];
    const float* W_fc2 = (const float*)d_in[11];
    const float* b_fc2 = (const float*)d_in[12];
    float* out = (float*)d_out;

    const int B = in_sizes[0] / (TS * 6);   // 1024
    lstm_mfma_kernel<<<B / 4, 1024, 0, stream>>>(
        x, W_ih0, W_hh0, b_ih0, b_hh0,
        W_ih1, W_hh1, b_ih1, b_hh1,
        W_fc1, b_fc1, W_fc2, b_fc2, out);
}